// Round 1
// baseline (592.496 us; speedup 1.0000x reference)
//
#include <hip/hip_runtime.h>
#include <math.h>

// ---------------------------------------------------------------------------
// 2-layer GCN (PyG GCNConv semantics) on MI355X.
//   deg[c]  = #incoming edges + 1 (self loop); dinv = rsqrt(deg)
//   g       = dinv[n] * (X @ W)            (GEMM + epilogue scale)
//   out[c]  = dinv[c] * (g[c] + sum_{(r,c) in E} g[r]) + b   (CSR gather)
//   layer1: ReLU; layer2: none, writes d_out.
// CSR (bucket-by-col) built once per call via counting sort; reused by both
// layers -> no float atomics anywhere.
// ---------------------------------------------------------------------------

#define BS 256

__global__ __launch_bounds__(BS) void count_kernel(const int* __restrict__ col,
                                                   int* __restrict__ cnt, int E) {
    int i = blockIdx.x * BS + threadIdx.x;
    if (i < E) atomicAdd(&cnt[col[i]], 1);
}

__global__ __launch_bounds__(BS) void scan_block_kernel(const int* __restrict__ cnt,
                                                        int* __restrict__ exc,
                                                        int* __restrict__ bsum, int N) {
    __shared__ int s[BS];
    int tid = threadIdx.x;
    int i = blockIdx.x * BS + tid;
    int v = (i < N) ? cnt[i] : 0;
    s[tid] = v;
    __syncthreads();
    for (int off = 1; off < BS; off <<= 1) {
        int t = (tid >= off) ? s[tid - off] : 0;
        __syncthreads();
        s[tid] += t;
        __syncthreads();
    }
    if (i < N) exc[i] = s[tid] - v;       // exclusive within block
    if (tid == BS - 1) bsum[blockIdx.x] = s[BS - 1];
}

__global__ __launch_bounds__(512) void scan_bsum_kernel(const int* __restrict__ bsum,
                                                        int* __restrict__ boff, int NB) {
    __shared__ int s[512];
    int tid = threadIdx.x;
    int v = (tid < NB) ? bsum[tid] : 0;
    s[tid] = v;
    __syncthreads();
    for (int off = 1; off < 512; off <<= 1) {
        int t = (tid >= off) ? s[tid - off] : 0;
        __syncthreads();
        s[tid] += t;
        __syncthreads();
    }
    if (tid < NB) boff[tid] = s[tid] - v; // exclusive across blocks
}

__global__ __launch_bounds__(BS) void add_off_kernel(int* __restrict__ exc,
                                                     const int* __restrict__ boff, int N) {
    int i = blockIdx.x * BS + threadIdx.x;
    if (i < N) exc[i] += boff[blockIdx.x];
}

__global__ __launch_bounds__(BS) void dinv_kernel(const int* __restrict__ cnt,
                                                  float* __restrict__ dinv, int N) {
    int i = blockIdx.x * BS + threadIdx.x;
    if (i < N) dinv[i] = rsqrtf((float)(cnt[i] + 1));
}

__global__ __launch_bounds__(BS) void scatter_kernel(const int* __restrict__ row,
                                                     const int* __restrict__ col,
                                                     const int* __restrict__ off,
                                                     int* __restrict__ cursor,
                                                     int* __restrict__ src, int E) {
    int i = blockIdx.x * BS + threadIdx.x;
    if (i >= E) return;
    int c = col[i];
    int p = off[c] + atomicAdd(&cursor[c], 1);
    src[p] = row[i];
}

// G[n][COLS] = dinv[n] * (A[n][128] @ W[128][COLS])
// COLS=128: CG=32 colgroups, RT=8 rowthreads, 32 rows/block, xs stride 128 (f4 stage)
// COLS=64 : CG=16, RT=16, 64 rows/block, xs stride 130 (f2 stage, pad kills 4-way bank conflict)
template <int COLS>
__global__ __launch_bounds__(BS) void gemm_scale_kernel(const float* __restrict__ A,
                                                        const float* __restrict__ W,
                                                        const float* __restrict__ dinv,
                                                        float* __restrict__ G, int n) {
    constexpr int K = 128;
    constexpr int CG = COLS / 4;
    constexpr int RT = BS / CG;
    constexpr int ROWS = RT * 4;
    constexpr int KS = (COLS == 64) ? (K + 2) : K;   // xs row stride in floats

    __shared__ float ws[K * COLS];
    __shared__ float xs[ROWS * KS];

    int tid = threadIdx.x;
    int r0 = blockIdx.x * ROWS;

    // W -> LDS (coalesced float4)
    const float4* W4 = (const float4*)W;
    float4* ws4 = (float4*)ws;
    for (int i = tid; i < K * CG; i += BS) ws4[i] = W4[i];

    // x tile -> LDS, row-major with stride KS
    for (int i = tid; i < ROWS * (K / 4); i += BS) {
        int r = i / (K / 4);
        int kq = i % (K / 4);
        int grow = r0 + r;
        float4 v = make_float4(0.f, 0.f, 0.f, 0.f);
        if (grow < n) v = ((const float4*)A)[(size_t)grow * (K / 4) + kq];
        if (COLS == 64) {
            float2* p = (float2*)(xs + r * KS + 4 * kq);
            p[0] = make_float2(v.x, v.y);
            p[1] = make_float2(v.z, v.w);
        } else {
            ((float4*)(xs + r * KS))[kq] = v;
        }
    }
    __syncthreads();

    int cg = tid % CG;
    int rt = tid / CG;
    float4 acc0 = make_float4(0, 0, 0, 0), acc1 = acc0, acc2 = acc0, acc3 = acc0;
    const float* x0 = xs + (rt * 4 + 0) * KS;
    const float* x1 = xs + (rt * 4 + 1) * KS;
    const float* x2 = xs + (rt * 4 + 2) * KS;
    const float* x3 = xs + (rt * 4 + 3) * KS;

#pragma unroll 4
    for (int k = 0; k < K; ++k) {
        float4 w4 = ws4[k * CG + cg];
        float a0 = x0[k], a1 = x1[k], a2 = x2[k], a3 = x3[k];
        acc0.x += w4.x * a0; acc0.y += w4.y * a0; acc0.z += w4.z * a0; acc0.w += w4.w * a0;
        acc1.x += w4.x * a1; acc1.y += w4.y * a1; acc1.z += w4.z * a1; acc1.w += w4.w * a1;
        acc2.x += w4.x * a2; acc2.y += w4.y * a2; acc2.z += w4.z * a2; acc2.w += w4.w * a2;
        acc3.x += w4.x * a3; acc3.y += w4.y * a3; acc3.z += w4.z * a3; acc3.w += w4.w * a3;
    }

    float4 accs[4] = {acc0, acc1, acc2, acc3};
#pragma unroll
    for (int j = 0; j < 4; ++j) {
        int grow = r0 + rt * 4 + j;
        if (grow < n) {
            float dv = dinv[grow];
            float4 o = make_float4(accs[j].x * dv, accs[j].y * dv,
                                   accs[j].z * dv, accs[j].w * dv);
            ((float4*)G)[(size_t)grow * CG + cg] = o;
        }
    }
}

// out[node][c] = act( dinv[node] * (G[node][c] + sum_{s in CSR(node)} G[s][c]) + b[c] )
template <int C, bool RELU>
__global__ __launch_bounds__(BS) void agg_kernel(const float* __restrict__ G,
                                                 const int* __restrict__ edge_off,
                                                 const int* __restrict__ cnt,
                                                 const int* __restrict__ src,
                                                 const float* __restrict__ dinv,
                                                 const float* __restrict__ bias,
                                                 float* __restrict__ out, int n) {
    constexpr int Gp = C / 4;          // float4 lanes per node
    constexpr int NPB = BS / Gp;       // nodes per block
    int lane = threadIdx.x % Gp;
    int li = threadIdx.x / Gp;
    int node = blockIdx.x * NPB + li;
    if (node >= n) return;

    const float4* G4 = (const float4*)G;
    float4 acc = G4[(size_t)node * Gp + lane];   // self-loop term
    int start = edge_off[node];
    int c = cnt[node];
    for (int i = 0; i < c; ++i) {
        int s = src[start + i];
        float4 v = G4[(size_t)s * Gp + lane];
        acc.x += v.x; acc.y += v.y; acc.z += v.z; acc.w += v.w;
    }
    float dv = dinv[node];
    float4 b4 = ((const float4*)bias)[lane];
    float4 o = make_float4(acc.x * dv + b4.x, acc.y * dv + b4.y,
                           acc.z * dv + b4.z, acc.w * dv + b4.w);
    if (RELU) {
        o.x = fmaxf(o.x, 0.f); o.y = fmaxf(o.y, 0.f);
        o.z = fmaxf(o.z, 0.f); o.w = fmaxf(o.w, 0.f);
    }
    ((float4*)out)[(size_t)node * Gp + lane] = o;
}

extern "C" void kernel_launch(void* const* d_in, const int* in_sizes, int n_in,
                              void* d_out, int out_size, void* d_ws, size_t ws_size,
                              hipStream_t stream) {
    const float* x  = (const float*)d_in[0];
    const int*   ei = (const int*)d_in[1];      // [2, E] int32
    const float* W1 = (const float*)d_in[2];
    const float* b1 = (const float*)d_in[3];
    const float* W2 = (const float*)d_in[4];
    const float* b2 = (const float*)d_in[5];

    const int IN_C = 128, HID_C = 128, OUT_C = 64;
    int n = in_sizes[0] / IN_C;
    int E = in_sizes[1] / 2;
    const int* row = ei;
    const int* col = ei + E;

    int NB = (n + BS - 1) / BS;

    // workspace carve-out (256B aligned)
    char* w = (char*)d_ws;
    auto alloc = [&](size_t bytes) {
        void* p = (void*)w;
        w += (bytes + 255) & ~(size_t)255;
        return p;
    };
    int*   cnt    = (int*)alloc((size_t)n * 4);
    int*   off    = (int*)alloc((size_t)n * 4);
    int*   cursor = (int*)alloc((size_t)n * 4);
    int*   bsum   = (int*)alloc((size_t)NB * 4);
    int*   boff   = (int*)alloc((size_t)NB * 4);
    int*   src    = (int*)alloc((size_t)E * 4);
    float* dinv   = (float*)alloc((size_t)n * 4);
    float* g      = (float*)alloc((size_t)n * HID_C * 4); // g1, reused as g2
    float* h1     = (float*)alloc((size_t)n * HID_C * 4);

    hipMemsetAsync(cnt, 0, (size_t)n * 4, stream);
    hipMemsetAsync(cursor, 0, (size_t)n * 4, stream);

    int gridE = (E + BS - 1) / BS;

    // degree + CSR build
    count_kernel<<<gridE, BS, 0, stream>>>(col, cnt, E);
    scan_block_kernel<<<NB, BS, 0, stream>>>(cnt, off, bsum, n);
    scan_bsum_kernel<<<1, 512, 0, stream>>>(bsum, boff, NB);
    add_off_kernel<<<NB, BS, 0, stream>>>(off, boff, n);
    dinv_kernel<<<NB, BS, 0, stream>>>(cnt, dinv, n);
    scatter_kernel<<<gridE, BS, 0, stream>>>(row, col, off, cursor, src, E);

    // layer 1: g1 = dinv * (x @ W1); h1 = relu(dinv*(g1_self + gather) + b1)
    gemm_scale_kernel<128><<<(n + 31) / 32, BS, 0, stream>>>(x, W1, dinv, g, n);
    agg_kernel<128, true><<<(n + 7) / 8, BS, 0, stream>>>(g, off, cnt, src, dinv, b1, h1, n);

    // layer 2: g2 = dinv * (h1 @ W2); out = dinv*(g2_self + gather) + b2
    gemm_scale_kernel<64><<<(n + 63) / 64, BS, 0, stream>>>(h1, W2, dinv, g, n);
    agg_kernel<64, false><<<(n + 15) / 16, BS, 0, stream>>>(g, off, cnt, src, dinv, b2,
                                                            (float*)d_out, n);
}

// Round 2
// 535.985 us; speedup vs baseline: 1.1054x; 1.1054x over previous
//
#include <hip/hip_runtime.h>
#include <math.h>

// ---------------------------------------------------------------------------
// 2-layer GCN (PyG GCNConv semantics) on MI355X.
//   deg[c]  = #incoming edges + 1 (self loop); dinv = rsqrt(deg)
//   g       = dinv[n] * (X @ W)            (GEMM + epilogue scale)
//   out[c]  = dinv[c] * (g[c] + sum_{(r,c) in E} g[r]) + b   (CSR gather)
//   layer1: ReLU; layer2: none, writes d_out.
// CSR built once per call via counting sort; no float atomics anywhere.
// R2: agg gather 8-way MLP unroll (was latency-bound at 1 outstanding/lane);
//     GEMM K-vectorized LDS reads (b128), xs stride 132 for COLS=64.
// ---------------------------------------------------------------------------

#define BS 256

__global__ __launch_bounds__(BS) void count_kernel(const int* __restrict__ col,
                                                   int* __restrict__ cnt, int E) {
    int i = blockIdx.x * BS + threadIdx.x;
    if (i < E) atomicAdd(&cnt[col[i]], 1);
}

__global__ __launch_bounds__(BS) void scan_block_kernel(const int* __restrict__ cnt,
                                                        int* __restrict__ exc,
                                                        int* __restrict__ bsum, int N) {
    __shared__ int s[BS];
    int tid = threadIdx.x;
    int i = blockIdx.x * BS + tid;
    int v = (i < N) ? cnt[i] : 0;
    s[tid] = v;
    __syncthreads();
    for (int off = 1; off < BS; off <<= 1) {
        int t = (tid >= off) ? s[tid - off] : 0;
        __syncthreads();
        s[tid] += t;
        __syncthreads();
    }
    if (i < N) exc[i] = s[tid] - v;       // exclusive within block
    if (tid == BS - 1) bsum[blockIdx.x] = s[BS - 1];
}

__global__ __launch_bounds__(512) void scan_bsum_kernel(const int* __restrict__ bsum,
                                                        int* __restrict__ boff, int NB) {
    __shared__ int s[512];
    int tid = threadIdx.x;
    int v = (tid < NB) ? bsum[tid] : 0;
    s[tid] = v;
    __syncthreads();
    for (int off = 1; off < 512; off <<= 1) {
        int t = (tid >= off) ? s[tid - off] : 0;
        __syncthreads();
        s[tid] += t;
        __syncthreads();
    }
    if (tid < NB) boff[tid] = s[tid] - v; // exclusive across blocks
}

__global__ __launch_bounds__(BS) void add_off_dinv_kernel(int* __restrict__ exc,
                                                          const int* __restrict__ boff,
                                                          const int* __restrict__ cnt,
                                                          float* __restrict__ dinv, int N) {
    int i = blockIdx.x * BS + threadIdx.x;
    if (i < N) {
        exc[i] += boff[blockIdx.x];
        dinv[i] = rsqrtf((float)(cnt[i] + 1));
    }
}

__global__ __launch_bounds__(BS) void scatter_kernel(const int* __restrict__ row,
                                                     const int* __restrict__ col,
                                                     const int* __restrict__ off,
                                                     int* __restrict__ cursor,
                                                     int* __restrict__ src, int E) {
    int i = blockIdx.x * BS + threadIdx.x;
    if (i >= E) return;
    int c = col[i];
    int p = off[c] + atomicAdd(&cursor[c], 1);
    src[p] = row[i];
}

// G[n][COLS] = dinv[n] * (A[n][128] @ W[128][COLS])
// COLS=128: CG=32, RT=8, 32 rows/block, KS=128 (2-way xs aliasing = free)
// COLS=64 : CG=16, RT=16, 64 rows/block, KS=132 (4 rt-groups -> pad to split banks)
template <int COLS>
__global__ __launch_bounds__(BS) void gemm_scale_kernel(const float* __restrict__ A,
                                                        const float* __restrict__ W,
                                                        const float* __restrict__ dinv,
                                                        float* __restrict__ G, int n) {
    constexpr int K = 128;
    constexpr int CG = COLS / 4;
    constexpr int RT = BS / CG;
    constexpr int ROWS = RT * 4;
    constexpr int KS = (COLS == 64) ? (K + 4) : K;   // xs row stride (floats), f4-aligned

    __shared__ float ws[K * COLS];
    __shared__ float xs[ROWS * KS];

    int tid = threadIdx.x;
    int r0 = blockIdx.x * ROWS;

    // W -> LDS (coalesced float4)
    const float4* W4 = (const float4*)W;
    float4* ws4 = (float4*)ws;
    for (int i = tid; i < K * CG; i += BS) ws4[i] = W4[i];

    // x tile -> LDS, row-major with stride KS
    for (int i = tid; i < ROWS * (K / 4); i += BS) {
        int r = i / (K / 4);
        int kq = i % (K / 4);
        int grow = r0 + r;
        float4 v = make_float4(0.f, 0.f, 0.f, 0.f);
        if (grow < n) v = ((const float4*)A)[(size_t)grow * (K / 4) + kq];
        ((float4*)(xs + r * KS))[kq] = v;
    }
    __syncthreads();

    int cg = tid % CG;
    int rt = tid / CG;
    const float4* xr0 = (const float4*)(xs + (rt * 4 + 0) * KS);
    const float4* xr1 = (const float4*)(xs + (rt * 4 + 1) * KS);
    const float4* xr2 = (const float4*)(xs + (rt * 4 + 2) * KS);
    const float4* xr3 = (const float4*)(xs + (rt * 4 + 3) * KS);

    float4 acc[4];
#pragma unroll
    for (int j = 0; j < 4; ++j) acc[j] = make_float4(0, 0, 0, 0);

#pragma unroll 2
    for (int kq = 0; kq < K / 4; ++kq) {
        float4 a0 = xr0[kq], a1 = xr1[kq], a2 = xr2[kq], a3 = xr3[kq];
        float4 w0 = ws4[(4 * kq + 0) * CG + cg];
        float4 w1 = ws4[(4 * kq + 1) * CG + cg];
        float4 w2 = ws4[(4 * kq + 2) * CG + cg];
        float4 w3 = ws4[(4 * kq + 3) * CG + cg];
#define FMA4(ac, a)                                                            \
        ac.x += a.x * w0.x + a.y * w1.x + a.z * w2.x + a.w * w3.x;             \
        ac.y += a.x * w0.y + a.y * w1.y + a.z * w2.y + a.w * w3.y;             \
        ac.z += a.x * w0.z + a.y * w1.z + a.z * w2.z + a.w * w3.z;             \
        ac.w += a.x * w0.w + a.y * w1.w + a.z * w2.w + a.w * w3.w;
        FMA4(acc[0], a0)
        FMA4(acc[1], a1)
        FMA4(acc[2], a2)
        FMA4(acc[3], a3)
#undef FMA4
    }

#pragma unroll
    for (int j = 0; j < 4; ++j) {
        int grow = r0 + rt * 4 + j;
        if (grow < n) {
            float dv = dinv[grow];
            float4 o = make_float4(acc[j].x * dv, acc[j].y * dv,
                                   acc[j].z * dv, acc[j].w * dv);
            ((float4*)G)[(size_t)grow * CG + cg] = o;
        }
    }
}

// out[node][c] = act( dinv[node] * (G[node][c] + sum_{s in CSR(node)} G[s][c]) + b[c] )
// 8-way MLP unroll: batch src reads (broadcast), 8 independent gathers in flight.
template <int C, bool RELU>
__global__ __launch_bounds__(BS) void agg_kernel(const float* __restrict__ G,
                                                 const int* __restrict__ edge_off,
                                                 const int* __restrict__ cnt,
                                                 const int* __restrict__ src,
                                                 const float* __restrict__ dinv,
                                                 const float* __restrict__ bias,
                                                 float* __restrict__ out, int n) {
    constexpr int Gp = C / 4;          // float4 lanes per node
    constexpr int NPB = BS / Gp;       // nodes per block
    int lane = threadIdx.x % Gp;
    int li = threadIdx.x / Gp;
    int node = blockIdx.x * NPB + li;
    if (node >= n) return;

    const float4* G4 = (const float4*)G;
    float4 acc = G4[node * Gp + lane];   // self-loop term
    float4 acc2 = make_float4(0, 0, 0, 0);
    const int* sp = src + edge_off[node];
    int deg = cnt[node];

    int i = 0;
    for (; i + 8 <= deg; i += 8) {
        int s0 = sp[i + 0], s1 = sp[i + 1], s2 = sp[i + 2], s3 = sp[i + 3];
        int s4 = sp[i + 4], s5 = sp[i + 5], s6 = sp[i + 6], s7 = sp[i + 7];
        float4 v0 = G4[s0 * Gp + lane];
        float4 v1 = G4[s1 * Gp + lane];
        float4 v2 = G4[s2 * Gp + lane];
        float4 v3 = G4[s3 * Gp + lane];
        float4 v4 = G4[s4 * Gp + lane];
        float4 v5 = G4[s5 * Gp + lane];
        float4 v6 = G4[s6 * Gp + lane];
        float4 v7 = G4[s7 * Gp + lane];
        acc.x += v0.x + v2.x + v4.x + v6.x;  acc2.x += v1.x + v3.x + v5.x + v7.x;
        acc.y += v0.y + v2.y + v4.y + v6.y;  acc2.y += v1.y + v3.y + v5.y + v7.y;
        acc.z += v0.z + v2.z + v4.z + v6.z;  acc2.z += v1.z + v3.z + v5.z + v7.z;
        acc.w += v0.w + v2.w + v4.w + v6.w;  acc2.w += v1.w + v3.w + v5.w + v7.w;
    }
    for (; i + 2 <= deg; i += 2) {
        int s0 = sp[i + 0], s1 = sp[i + 1];
        float4 v0 = G4[s0 * Gp + lane];
        float4 v1 = G4[s1 * Gp + lane];
        acc.x += v0.x; acc.y += v0.y; acc.z += v0.z; acc.w += v0.w;
        acc2.x += v1.x; acc2.y += v1.y; acc2.z += v1.z; acc2.w += v1.w;
    }
    if (i < deg) {
        int s0 = sp[i];
        float4 v0 = G4[s0 * Gp + lane];
        acc.x += v0.x; acc.y += v0.y; acc.z += v0.z; acc.w += v0.w;
    }
    acc.x += acc2.x; acc.y += acc2.y; acc.z += acc2.z; acc.w += acc2.w;

    float dv = dinv[node];
    float4 b4 = ((const float4*)bias)[lane];
    float4 o = make_float4(acc.x * dv + b4.x, acc.y * dv + b4.y,
                           acc.z * dv + b4.z, acc.w * dv + b4.w);
    if (RELU) {
        o.x = fmaxf(o.x, 0.f); o.y = fmaxf(o.y, 0.f);
        o.z = fmaxf(o.z, 0.f); o.w = fmaxf(o.w, 0.f);
    }
    ((float4*)out)[node * Gp + lane] = o;
}

extern "C" void kernel_launch(void* const* d_in, const int* in_sizes, int n_in,
                              void* d_out, int out_size, void* d_ws, size_t ws_size,
                              hipStream_t stream) {
    const float* x  = (const float*)d_in[0];
    const int*   ei = (const int*)d_in[1];      // [2, E] int32
    const float* W1 = (const float*)d_in[2];
    const float* b1 = (const float*)d_in[3];
    const float* W2 = (const float*)d_in[4];
    const float* b2 = (const float*)d_in[5];

    const int IN_C = 128, HID_C = 128;
    int n = in_sizes[0] / IN_C;
    int E = in_sizes[1] / 2;
    const int* row = ei;
    const int* col = ei + E;

    int NB = (n + BS - 1) / BS;

    // workspace carve-out (256B aligned)
    char* w = (char*)d_ws;
    auto alloc = [&](size_t bytes) {
        void* p = (void*)w;
        w += (bytes + 255) & ~(size_t)255;
        return p;
    };
    int*   cnt    = (int*)alloc((size_t)n * 4);
    int*   off    = (int*)alloc((size_t)n * 4);
    int*   cursor = (int*)alloc((size_t)n * 4);
    int*   bsum   = (int*)alloc((size_t)NB * 4);
    int*   boff   = (int*)alloc((size_t)NB * 4);
    int*   src    = (int*)alloc((size_t)E * 4);
    float* dinv   = (float*)alloc((size_t)n * 4);
    float* g      = (float*)alloc((size_t)n * HID_C * 4); // g1, reused as g2
    float* h1     = (float*)alloc((size_t)n * HID_C * 4);

    hipMemsetAsync(cnt, 0, (size_t)n * 4, stream);
    hipMemsetAsync(cursor, 0, (size_t)n * 4, stream);

    int gridE = (E + BS - 1) / BS;

    // degree + CSR build
    count_kernel<<<gridE, BS, 0, stream>>>(col, cnt, E);
    scan_block_kernel<<<NB, BS, 0, stream>>>(cnt, off, bsum, n);
    scan_bsum_kernel<<<1, 512, 0, stream>>>(bsum, boff, NB);
    add_off_dinv_kernel<<<NB, BS, 0, stream>>>(off, boff, cnt, dinv, n);
    scatter_kernel<<<gridE, BS, 0, stream>>>(row, col, off, cursor, src, E);

    // layer 1: g1 = dinv * (x @ W1); h1 = relu(dinv*(g1_self + gather) + b1)
    gemm_scale_kernel<128><<<(n + 31) / 32, BS, 0, stream>>>(x, W1, dinv, g, n);
    agg_kernel<128, true><<<(n + 7) / 8, BS, 0, stream>>>(g, off, cnt, src, dinv, b1, h1, n);

    // layer 2: g2 = dinv * (h1 @ W2); out = dinv*(g2_self + gather) + b2
    gemm_scale_kernel<64><<<(n + 63) / 64, BS, 0, stream>>>(h1, W2, dinv, g, n);
    agg_kernel<64, false><<<(n + 15) / 16, BS, 0, stream>>>(g, off, cnt, src, dinv, b2,
                                                            (float*)d_out, n);
}

// Round 3
// 471.623 us; speedup vs baseline: 1.2563x; 1.1365x over previous
//
#include <hip/hip_runtime.h>
#include <math.h>

// ---------------------------------------------------------------------------
// 2-layer GCN (PyG GCNConv semantics) on MI355X.
//   deg[c]  = #incoming edges + 1 (self loop); dinv = rsqrt(deg)
//   g       = bf16( dinv[n] * (X @ W) )     (GEMM + epilogue scale + pack)
//   out[c]  = dinv[c] * (g[c] + sum_{(r,c) in E} g[r]) + b   (CSR gather)
//   layer1: ReLU -> h1 (fp32); layer2: none, writes d_out (fp32).
// CSR built once per call via counting sort; no float atomics anywhere.
// R3: g stored in bf16 -> halves gather bytes AND cache lines per edge
//     (the agg kernel is L1-miss-queue / EA-traffic bound, not lane-latency
//     bound -- R2's deeper MLP barely moved it).
// ---------------------------------------------------------------------------

#define BS 256

__device__ __forceinline__ unsigned pack_bf16x2(float a, float b) {
    unsigned ua = __float_as_uint(a);
    unsigned ub = __float_as_uint(b);
    ua = (ua + 0x7fffu + ((ua >> 16) & 1u)) >> 16;   // RTE
    ub = (ub + 0x7fffu + ((ub >> 16) & 1u)) >> 16;
    return ua | (ub << 16);
}

__device__ __forceinline__ float bf_lo(unsigned u) { return __uint_as_float(u << 16); }
__device__ __forceinline__ float bf_hi(unsigned u) { return __uint_as_float(u & 0xffff0000u); }

__global__ __launch_bounds__(BS) void count_kernel(const int* __restrict__ col,
                                                   int* __restrict__ cnt, int E) {
    int i = blockIdx.x * BS + threadIdx.x;
    if (i < E) atomicAdd(&cnt[col[i]], 1);
}

__global__ __launch_bounds__(BS) void scan_block_kernel(const int* __restrict__ cnt,
                                                        int* __restrict__ exc,
                                                        int* __restrict__ bsum, int N) {
    __shared__ int s[BS];
    int tid = threadIdx.x;
    int i = blockIdx.x * BS + tid;
    int v = (i < N) ? cnt[i] : 0;
    s[tid] = v;
    __syncthreads();
    for (int off = 1; off < BS; off <<= 1) {
        int t = (tid >= off) ? s[tid - off] : 0;
        __syncthreads();
        s[tid] += t;
        __syncthreads();
    }
    if (i < N) exc[i] = s[tid] - v;       // exclusive within block
    if (tid == BS - 1) bsum[blockIdx.x] = s[BS - 1];
}

__global__ __launch_bounds__(512) void scan_bsum_kernel(const int* __restrict__ bsum,
                                                        int* __restrict__ boff, int NB) {
    __shared__ int s[512];
    int tid = threadIdx.x;
    int v = (tid < NB) ? bsum[tid] : 0;
    s[tid] = v;
    __syncthreads();
    for (int off = 1; off < 512; off <<= 1) {
        int t = (tid >= off) ? s[tid - off] : 0;
        __syncthreads();
        s[tid] += t;
        __syncthreads();
    }
    if (tid < NB) boff[tid] = s[tid] - v; // exclusive across blocks
}

__global__ __launch_bounds__(BS) void add_off_dinv_kernel(int* __restrict__ exc,
                                                          const int* __restrict__ boff,
                                                          const int* __restrict__ cnt,
                                                          float* __restrict__ dinv, int N) {
    int i = blockIdx.x * BS + threadIdx.x;
    if (i < N) {
        exc[i] += boff[blockIdx.x];
        dinv[i] = rsqrtf((float)(cnt[i] + 1));
    }
}

__global__ __launch_bounds__(BS) void scatter_kernel(const int* __restrict__ row,
                                                     const int* __restrict__ col,
                                                     const int* __restrict__ off,
                                                     int* __restrict__ cursor,
                                                     int* __restrict__ src, int E) {
    int i = blockIdx.x * BS + threadIdx.x;
    if (i >= E) return;
    int c = col[i];
    int p = off[c] + atomicAdd(&cursor[c], 1);
    src[p] = row[i];
}

// G[n][COLS] (bf16, packed pairs) = bf16( dinv[n] * (A[n][128] @ W[128][COLS]) )
template <int COLS>
__global__ __launch_bounds__(BS) void gemm_scale_kernel(const float* __restrict__ A,
                                                        const float* __restrict__ W,
                                                        const float* __restrict__ dinv,
                                                        unsigned* __restrict__ G, int n) {
    constexpr int K = 128;
    constexpr int CG = COLS / 4;
    constexpr int RT = BS / CG;
    constexpr int ROWS = RT * 4;
    constexpr int KS = (COLS == 64) ? (K + 4) : K;   // xs row stride (floats)

    __shared__ float ws[K * COLS];
    __shared__ float xs[ROWS * KS];

    int tid = threadIdx.x;
    int r0 = blockIdx.x * ROWS;

    const float4* W4 = (const float4*)W;
    float4* ws4 = (float4*)ws;
    for (int i = tid; i < K * CG; i += BS) ws4[i] = W4[i];

    for (int i = tid; i < ROWS * (K / 4); i += BS) {
        int r = i / (K / 4);
        int kq = i % (K / 4);
        int grow = r0 + r;
        float4 v = make_float4(0.f, 0.f, 0.f, 0.f);
        if (grow < n) v = ((const float4*)A)[(size_t)grow * (K / 4) + kq];
        ((float4*)(xs + r * KS))[kq] = v;
    }
    __syncthreads();

    int cg = tid % CG;
    int rt = tid / CG;
    const float4* xr0 = (const float4*)(xs + (rt * 4 + 0) * KS);
    const float4* xr1 = (const float4*)(xs + (rt * 4 + 1) * KS);
    const float4* xr2 = (const float4*)(xs + (rt * 4 + 2) * KS);
    const float4* xr3 = (const float4*)(xs + (rt * 4 + 3) * KS);

    float4 acc[4];
#pragma unroll
    for (int j = 0; j < 4; ++j) acc[j] = make_float4(0, 0, 0, 0);

#pragma unroll 2
    for (int kq = 0; kq < K / 4; ++kq) {
        float4 a0 = xr0[kq], a1 = xr1[kq], a2 = xr2[kq], a3 = xr3[kq];
        float4 w0 = ws4[(4 * kq + 0) * CG + cg];
        float4 w1 = ws4[(4 * kq + 1) * CG + cg];
        float4 w2 = ws4[(4 * kq + 2) * CG + cg];
        float4 w3 = ws4[(4 * kq + 3) * CG + cg];
#define FMA4(ac, a)                                                            \
        ac.x += a.x * w0.x + a.y * w1.x + a.z * w2.x + a.w * w3.x;             \
        ac.y += a.x * w0.y + a.y * w1.y + a.z * w2.y + a.w * w3.y;             \
        ac.z += a.x * w0.z + a.y * w1.z + a.z * w2.z + a.w * w3.z;             \
        ac.w += a.x * w0.w + a.y * w1.w + a.z * w2.w + a.w * w3.w;
        FMA4(acc[0], a0)
        FMA4(acc[1], a1)
        FMA4(acc[2], a2)
        FMA4(acc[3], a3)
#undef FMA4
    }

#pragma unroll
    for (int j = 0; j < 4; ++j) {
        int grow = r0 + rt * 4 + j;
        if (grow < n) {
            float dv = dinv[grow];
            uint2 o;
            o.x = pack_bf16x2(acc[j].x * dv, acc[j].y * dv);
            o.y = pack_bf16x2(acc[j].z * dv, acc[j].w * dv);
            ((uint2*)(G + (size_t)grow * (COLS / 2)))[cg] = o;
        }
    }
}

// out[node][c] = act( dinv[node] * (G[node][c] + sum_{s in CSR(node)} G[s][c]) + b[c] )
// G is bf16-packed; each lane covers 8 channels (one uint4). 8-deep gather MLP.
template <int C, bool RELU>
__global__ __launch_bounds__(BS) void agg_kernel(const unsigned* __restrict__ G,
                                                 const int* __restrict__ edge_off,
                                                 const int* __restrict__ cnt,
                                                 const int* __restrict__ src,
                                                 const float* __restrict__ dinv,
                                                 const float* __restrict__ bias,
                                                 float* __restrict__ out, int n) {
    constexpr int Gp = C / 8;          // uint4 lanes per node (8 bf16 each)
    constexpr int NPB = BS / Gp;       // nodes per block
    int lane = threadIdx.x % Gp;
    int li = threadIdx.x / Gp;
    int node = blockIdx.x * NPB + li;
    if (node >= n) return;

    const uint4* G4 = (const uint4*)G;
    float acc[8];
    {
        uint4 sv = G4[(size_t)node * Gp + lane];   // self-loop term
        acc[0] = bf_lo(sv.x); acc[1] = bf_hi(sv.x);
        acc[2] = bf_lo(sv.y); acc[3] = bf_hi(sv.y);
        acc[4] = bf_lo(sv.z); acc[5] = bf_hi(sv.z);
        acc[6] = bf_lo(sv.w); acc[7] = bf_hi(sv.w);
    }
    const int* sp = src + edge_off[node];
    int deg = cnt[node];

#define ACCUM(v)                                                               \
    acc[0] += bf_lo(v.x); acc[1] += bf_hi(v.x);                                \
    acc[2] += bf_lo(v.y); acc[3] += bf_hi(v.y);                                \
    acc[4] += bf_lo(v.z); acc[5] += bf_hi(v.z);                                \
    acc[6] += bf_lo(v.w); acc[7] += bf_hi(v.w);

    int i = 0;
    for (; i + 8 <= deg; i += 8) {
        int s0 = sp[i + 0], s1 = sp[i + 1], s2 = sp[i + 2], s3 = sp[i + 3];
        int s4 = sp[i + 4], s5 = sp[i + 5], s6 = sp[i + 6], s7 = sp[i + 7];
        uint4 v0 = G4[(size_t)s0 * Gp + lane];
        uint4 v1 = G4[(size_t)s1 * Gp + lane];
        uint4 v2 = G4[(size_t)s2 * Gp + lane];
        uint4 v3 = G4[(size_t)s3 * Gp + lane];
        uint4 v4 = G4[(size_t)s4 * Gp + lane];
        uint4 v5 = G4[(size_t)s5 * Gp + lane];
        uint4 v6 = G4[(size_t)s6 * Gp + lane];
        uint4 v7 = G4[(size_t)s7 * Gp + lane];
        ACCUM(v0) ACCUM(v1) ACCUM(v2) ACCUM(v3)
        ACCUM(v4) ACCUM(v5) ACCUM(v6) ACCUM(v7)
    }
    for (; i + 2 <= deg; i += 2) {
        int s0 = sp[i + 0], s1 = sp[i + 1];
        uint4 v0 = G4[(size_t)s0 * Gp + lane];
        uint4 v1 = G4[(size_t)s1 * Gp + lane];
        ACCUM(v0) ACCUM(v1)
    }
    if (i < deg) {
        uint4 v0 = G4[(size_t)sp[i] * Gp + lane];
        ACCUM(v0)
    }
#undef ACCUM

    float dv = dinv[node];
    const float4* b4 = (const float4*)bias;
    float4 bl = b4[2 * lane + 0], bh = b4[2 * lane + 1];
    float4 o0 = make_float4(acc[0] * dv + bl.x, acc[1] * dv + bl.y,
                            acc[2] * dv + bl.z, acc[3] * dv + bl.w);
    float4 o1 = make_float4(acc[4] * dv + bh.x, acc[5] * dv + bh.y,
                            acc[6] * dv + bh.z, acc[7] * dv + bh.w);
    if (RELU) {
        o0.x = fmaxf(o0.x, 0.f); o0.y = fmaxf(o0.y, 0.f);
        o0.z = fmaxf(o0.z, 0.f); o0.w = fmaxf(o0.w, 0.f);
        o1.x = fmaxf(o1.x, 0.f); o1.y = fmaxf(o1.y, 0.f);
        o1.z = fmaxf(o1.z, 0.f); o1.w = fmaxf(o1.w, 0.f);
    }
    float4* orow = (float4*)(out + (size_t)node * C);
    orow[2 * lane + 0] = o0;
    orow[2 * lane + 1] = o1;
}

extern "C" void kernel_launch(void* const* d_in, const int* in_sizes, int n_in,
                              void* d_out, int out_size, void* d_ws, size_t ws_size,
                              hipStream_t stream) {
    const float* x  = (const float*)d_in[0];
    const int*   ei = (const int*)d_in[1];      // [2, E] int32
    const float* W1 = (const float*)d_in[2];
    const float* b1 = (const float*)d_in[3];
    const float* W2 = (const float*)d_in[4];
    const float* b2 = (const float*)d_in[5];

    const int IN_C = 128, HID_C = 128;
    int n = in_sizes[0] / IN_C;
    int E = in_sizes[1] / 2;
    const int* row = ei;
    const int* col = ei + E;

    int NB = (n + BS - 1) / BS;

    char* w = (char*)d_ws;
    auto alloc = [&](size_t bytes) {
        void* p = (void*)w;
        w += (bytes + 255) & ~(size_t)255;
        return p;
    };
    int*      cnt    = (int*)alloc((size_t)n * 4);
    int*      off    = (int*)alloc((size_t)n * 4);
    int*      cursor = (int*)alloc((size_t)n * 4);
    int*      bsum   = (int*)alloc((size_t)NB * 4);
    int*      boff   = (int*)alloc((size_t)NB * 4);
    int*      src    = (int*)alloc((size_t)E * 4);
    float*    dinv   = (float*)alloc((size_t)n * 4);
    unsigned* g      = (unsigned*)alloc((size_t)n * HID_C * 2);  // bf16-packed
    float*    h1     = (float*)alloc((size_t)n * HID_C * 4);

    hipMemsetAsync(cnt, 0, (size_t)n * 4, stream);
    hipMemsetAsync(cursor, 0, (size_t)n * 4, stream);

    int gridE = (E + BS - 1) / BS;

    // degree + CSR build
    count_kernel<<<gridE, BS, 0, stream>>>(col, cnt, E);
    scan_block_kernel<<<NB, BS, 0, stream>>>(cnt, off, bsum, n);
    scan_bsum_kernel<<<1, 512, 0, stream>>>(bsum, boff, NB);
    add_off_dinv_kernel<<<NB, BS, 0, stream>>>(off, boff, cnt, dinv, n);
    scatter_kernel<<<gridE, BS, 0, stream>>>(row, col, off, cursor, src, E);

    // layer 1: g1 = bf16(dinv * (x @ W1)); h1 = relu(dinv*(self + gather) + b1)
    gemm_scale_kernel<128><<<(n + 31) / 32, BS, 0, stream>>>(x, W1, dinv, g, n);
    agg_kernel<128, true><<<(n + 15) / 16, BS, 0, stream>>>(g, off, cnt, src, dinv, b1, h1, n);

    // layer 2: g2 = bf16(dinv * (h1 @ W2)); out = dinv*(self + gather) + b2
    gemm_scale_kernel<64><<<(n + 63) / 64, BS, 0, stream>>>(h1, W2, dinv, g, n);
    agg_kernel<64, false><<<(n + 31) / 32, BS, 0, stream>>>(g, off, cnt, src, dinv, b2,
                                                            (float*)d_out, n);
}